// Round 1
// baseline (1031.351 us; speedup 1.0000x reference)
//
#include <hip/hip_runtime.h>

#define N_NODES 16384
#define N_EDGES 131072
#define MUL 64
#define HIDDEN 64
#define NUM_IRREPS 384      // 6*MUL
#define TE 64               // edges per block in MLP kernel

#define INV_SQRT3   0.5773502691896258f
#define INV_SQRT8   0.35355339059327373f   // 1/sqrt(N_RADIAL), also 1/sqrt(AVG_NUM_NEIGHBORS)
#define SC3         (0.125f * 0.35355339059327373f)  // (1/sqrt(HIDDEN)) * (1/sqrt(avg_neighbors))

__device__ __forceinline__ float silu_f(float x) {
    return x / (1.0f + __expf(-x));
}

// ---------------------------------------------------------------------------
// Kernel 1: per-edge radial MLP producing w[e][384] (all scale factors folded)
// Block = 256 threads, TE=64 edges. LDS-staged weights, register-tiled GEMM.
// ---------------------------------------------------------------------------
__global__ __launch_bounds__(256) void mlp_kernel(
    const float* __restrict__ radial,   // (E, 8)
    const float* __restrict__ w1,       // (8, 64)
    const float* __restrict__ w2,       // (64, 64)
    const float* __restrict__ w3,       // (64, 384)
    float* __restrict__ wout,           // (chunk, 384), local-chunk indexed
    int e_begin)
{
    __shared__ float w1s[8 * 64];       // 2 KB
    __shared__ float rs[TE * 9];        // padded stride 9, ~2.25 KB
    __shared__ float h2s[TE * 65];      // padded stride 65, ~16.25 KB
    __shared__ float bufA[8256];        // phase A: w2s[4096] + h1s[64*65]; phase 3: w3 chunk [64*128]
    float* const w2s = bufA;
    float* const h1s = bufA + 4096;
    float* const w3s = bufA;

    const int t  = threadIdx.x;
    const int le0 = blockIdx.x * TE;          // local edge base (within chunk)
    const int e0  = e_begin + le0;            // global edge base

    // ---- stage weights + radial tile ----
    for (int i = t; i < 512; i += 256) w1s[i] = w1[i];
    for (int i = t; i < 4096; i += 256) w2s[i] = w2[i];
    for (int i = t; i < 512; i += 256) {
        int e = i >> 3, k = i & 7;
        rs[e * 9 + k] = radial[(size_t)e0 * 8 + i];
    }
    __syncthreads();

    // ---- phase 1: h1 = silu(r @ w1 * 1/sqrt(8)) ----
    {
        const int e  = t >> 2;            // 0..63
        const int j0 = (t & 3) * 16;      // 4 groups of 16 hidden units
        float acc[16];
#pragma unroll
        for (int j = 0; j < 16; ++j) acc[j] = 0.0f;
#pragma unroll
        for (int k = 0; k < 8; ++k) {
            float rv = rs[e * 9 + k];
#pragma unroll
            for (int j = 0; j < 16; ++j)
                acc[j] += rv * w1s[k * 64 + j0 + j];
        }
#pragma unroll
        for (int j = 0; j < 16; ++j)
            h1s[e * 65 + j0 + j] = silu_f(acc[j] * INV_SQRT8);
    }
    __syncthreads();

    // ---- phase 2: h2 = silu(h1 @ w2 * 1/8) ----
    {
        const int e  = t >> 2;
        const int j0 = (t & 3) * 16;
        float acc[16];
#pragma unroll
        for (int j = 0; j < 16; ++j) acc[j] = 0.0f;
        for (int k = 0; k < 64; ++k) {
            float hv = h1s[e * 65 + k];
            const float4 wv0 = *(const float4*)&w2s[k * 64 + j0];
            const float4 wv1 = *(const float4*)&w2s[k * 64 + j0 + 4];
            const float4 wv2 = *(const float4*)&w2s[k * 64 + j0 + 8];
            const float4 wv3 = *(const float4*)&w2s[k * 64 + j0 + 12];
            acc[0]  += hv * wv0.x; acc[1]  += hv * wv0.y; acc[2]  += hv * wv0.z; acc[3]  += hv * wv0.w;
            acc[4]  += hv * wv1.x; acc[5]  += hv * wv1.y; acc[6]  += hv * wv1.z; acc[7]  += hv * wv1.w;
            acc[8]  += hv * wv2.x; acc[9]  += hv * wv2.y; acc[10] += hv * wv2.z; acc[11] += hv * wv2.w;
            acc[12] += hv * wv3.x; acc[13] += hv * wv3.y; acc[14] += hv * wv3.z; acc[15] += hv * wv3.w;
        }
#pragma unroll
        for (int j = 0; j < 16; ++j)
            h2s[e * 65 + j0 + j] = silu_f(acc[j] * 0.125f);
    }

    // ---- phase 3: w = h2 @ w3 * SC3, in 3 chunks of 128 output cols ----
    for (int c = 0; c < 3; ++c) {
        __syncthreads();   // previous phase readers done before overwriting bufA
        for (int i = t; i < 8192; i += 256) {
            int row = i >> 7, col = i & 127;
            w3s[i] = w3[row * 384 + c * 128 + col];
        }
        __syncthreads();

        const int eg = t >> 4;         // 0..15 -> 4 edges each
        const int o0 = (t & 15) * 8;   // 16 groups of 8 outputs
        float acc[4][8];
#pragma unroll
        for (int i = 0; i < 4; ++i)
#pragma unroll
            for (int j = 0; j < 8; ++j) acc[i][j] = 0.0f;

#pragma unroll 4
        for (int k = 0; k < 64; ++k) {
            const float4 wv0 = *(const float4*)&w3s[k * 128 + o0];
            const float4 wv1 = *(const float4*)&w3s[k * 128 + o0 + 4];
#pragma unroll
            for (int i = 0; i < 4; ++i) {
                float hv = h2s[(eg * 4 + i) * 65 + k];
                acc[i][0] += hv * wv0.x; acc[i][1] += hv * wv0.y;
                acc[i][2] += hv * wv0.z; acc[i][3] += hv * wv0.w;
                acc[i][4] += hv * wv1.x; acc[i][5] += hv * wv1.y;
                acc[i][6] += hv * wv1.z; acc[i][7] += hv * wv1.w;
            }
        }
#pragma unroll
        for (int i = 0; i < 4; ++i) {
            const size_t le = (size_t)(le0 + eg * 4 + i);
            float4 s0, s1;
            s0.x = acc[i][0] * SC3; s0.y = acc[i][1] * SC3;
            s0.z = acc[i][2] * SC3; s0.w = acc[i][3] * SC3;
            s1.x = acc[i][4] * SC3; s1.y = acc[i][5] * SC3;
            s1.z = acc[i][6] * SC3; s1.w = acc[i][7] * SC3;
            *(float4*)&wout[le * 384 + c * 128 + o0]     = s0;
            *(float4*)&wout[le * 384 + c * 128 + o0 + 4] = s1;
        }
    }
}

// ---------------------------------------------------------------------------
// Kernel 2: gather sender feats, tensor product, scale by w, scatter-add.
// One wave (64 lanes) per edge; lane = channel m.
// ---------------------------------------------------------------------------
__global__ __launch_bounds__(256) void scatter_kernel(
    const float* __restrict__ node_feats,     // (N, 256)
    const float* __restrict__ edge_features,  // (E, 4)
    const float* __restrict__ wbuf,           // (chunk, 384), local-chunk indexed
    const int* __restrict__ senders,
    const int* __restrict__ receivers,
    float* __restrict__ out,                  // (N, 768)
    int e_begin, int e_count)
{
    const int wid  = threadIdx.x >> 6;
    const int lane = threadIdx.x & 63;
    const int le   = blockIdx.x * 4 + wid;    // local edge
    if (le >= e_count) return;
    const int e = e_begin + le;

    const int sidx = senders[e];
    const int ridx = receivers[e];
    const float es  = edge_features[e * 4 + 0];
    const float ev0 = edge_features[e * 4 + 1];
    const float ev1 = edge_features[e * 4 + 2];
    const float ev2 = edge_features[e * 4 + 3];

    const float* nf = node_feats + (size_t)sidx * 256;
    const float s  = nf[lane];
    const float v0 = nf[64 + lane * 3 + 0];
    const float v1 = nf[64 + lane * 3 + 1];
    const float v2 = nf[64 + lane * 3 + 2];

    const float* wp = wbuf + (size_t)le * 384;
    const float ws0 = wp[lane];          // s_e
    const float ws1 = wp[64 + lane];     // tp_s1
    const float ws2 = wp[128 + lane];    // tp_s2
    const float wv0 = wp[192 + lane];    // v_e
    const float wv1 = wp[256 + lane];    // tp_v1
    const float wv2 = wp[320 + lane];    // tp_v2

    const float dot = (v0 * ev0 + v1 * ev1 + v2 * ev2) * INV_SQRT3;

    float* orow = out + (size_t)ridx * 768;
    // scalar part: [0:64]=s_e, [64:128]=s_e*es, [128:192]=dot
    atomicAdd(&orow[lane],       s * ws0);
    atomicAdd(&orow[64 + lane],  s * es * ws1);
    atomicAdd(&orow[128 + lane], dot * ws2);
    // vector part: out[192 + ch*3 + c]; ch: [0:64]=v_e, [64:128]=s_e*ev, [128:192]=v_e*es
    {
        const int b = 192 + lane * 3;
        atomicAdd(&orow[b + 0], v0 * wv0);
        atomicAdd(&orow[b + 1], v1 * wv0);
        atomicAdd(&orow[b + 2], v2 * wv0);
    }
    {
        const int b = 192 + (64 + lane) * 3;
        const float sw = s * wv1;
        atomicAdd(&orow[b + 0], ev0 * sw);
        atomicAdd(&orow[b + 1], ev1 * sw);
        atomicAdd(&orow[b + 2], ev2 * sw);
    }
    {
        const int b = 192 + (128 + lane) * 3;
        const float esw = es * wv2;
        atomicAdd(&orow[b + 0], v0 * esw);
        atomicAdd(&orow[b + 1], v1 * esw);
        atomicAdd(&orow[b + 2], v2 * esw);
    }
}

// ---------------------------------------------------------------------------
extern "C" void kernel_launch(void* const* d_in, const int* in_sizes, int n_in,
                              void* d_out, int out_size, void* d_ws, size_t ws_size,
                              hipStream_t stream) {
    const float* node_feats    = (const float*)d_in[0];
    const float* edge_features = (const float*)d_in[1];
    const float* radial        = (const float*)d_in[2];
    const float* w1            = (const float*)d_in[3];
    const float* w2            = (const float*)d_in[4];
    const float* w3            = (const float*)d_in[5];
    const int*   senders       = (const int*)d_in[6];
    const int*   receivers     = (const int*)d_in[7];
    float* out  = (float*)d_out;
    float* wbuf = (float*)d_ws;

    // Output is accumulated via atomics -> zero it first (harness poisons 0xAA).
    hipMemsetAsync(d_out, 0, (size_t)out_size * sizeof(float), stream);

    // Chunk edges through workspace (w = chunk x 384 fp32).
    size_t max_chunk = ws_size / (NUM_IRREPS * sizeof(float));
    max_chunk &= ~(size_t)(TE - 1);          // multiple of TE
    int chunk = (max_chunk >= (size_t)N_EDGES) ? N_EDGES
              : (max_chunk < (size_t)TE ? TE : (int)max_chunk);

    for (int e0 = 0; e0 < N_EDGES; e0 += chunk) {
        int cnt = N_EDGES - e0;
        if (cnt > chunk) cnt = chunk;
        int nb1 = (cnt + TE - 1) / TE;
        mlp_kernel<<<nb1, 256, 0, stream>>>(radial, w1, w2, w3, wbuf, e0);
        int nb2 = (cnt + 3) / 4;
        scatter_kernel<<<nb2, 256, 0, stream>>>(node_feats, edge_features, wbuf,
                                                senders, receivers, out, e0, cnt);
    }
}

// Round 2
// 301.554 us; speedup vs baseline: 3.4201x; 3.4201x over previous
//
#include <hip/hip_runtime.h>

#define N_NODES 16384
#define N_EDGES 131072
#define MUL 64
#define HIDDEN 64
#define NUM_IRREPS 384      // 6*MUL
#define TE 64               // edges per block in MLP kernel

#define INV_SQRT3   0.5773502691896258f
#define INV_SQRT8   0.35355339059327373f   // 1/sqrt(N_RADIAL)
#define SC3         (0.125f * 0.35355339059327373f)  // (1/sqrt(HIDDEN)) * (1/sqrt(avg_neighbors))

__device__ __forceinline__ float silu_f(float x) {
    return x / (1.0f + __expf(-x));
}

// ---------------------------------------------------------------------------
// Kernel 1: per-edge radial MLP producing w[e][384] (all scale factors folded)
// ---------------------------------------------------------------------------
__global__ __launch_bounds__(256) void mlp_kernel(
    const float* __restrict__ radial,   // (E, 8)
    const float* __restrict__ w1,       // (8, 64)
    const float* __restrict__ w2,       // (64, 64)
    const float* __restrict__ w3,       // (64, 384)
    float* __restrict__ wout,           // (chunk, 384), local-chunk indexed
    int e_begin)
{
    __shared__ float w1s[8 * 64];
    __shared__ float rs[TE * 9];
    __shared__ float h2s[TE * 65];
    __shared__ float bufA[8256];        // phase A: w2s[4096]+h1s[64*65]; phase 3: w3 chunk
    float* const w2s = bufA;
    float* const h1s = bufA + 4096;
    float* const w3s = bufA;

    const int t   = threadIdx.x;
    const int le0 = blockIdx.x * TE;
    const int e0  = e_begin + le0;

    for (int i = t; i < 512; i += 256) w1s[i] = w1[i];
    for (int i = t; i < 4096; i += 256) w2s[i] = w2[i];
    for (int i = t; i < 512; i += 256) {
        int e = i >> 3, k = i & 7;
        rs[e * 9 + k] = radial[(size_t)e0 * 8 + i];
    }
    __syncthreads();

    // phase 1: h1 = silu(r @ w1 / sqrt(8))
    {
        const int e  = t >> 2;
        const int j0 = (t & 3) * 16;
        float acc[16];
#pragma unroll
        for (int j = 0; j < 16; ++j) acc[j] = 0.0f;
#pragma unroll
        for (int k = 0; k < 8; ++k) {
            float rv = rs[e * 9 + k];
#pragma unroll
            for (int j = 0; j < 16; ++j)
                acc[j] += rv * w1s[k * 64 + j0 + j];
        }
#pragma unroll
        for (int j = 0; j < 16; ++j)
            h1s[e * 65 + j0 + j] = silu_f(acc[j] * INV_SQRT8);
    }
    __syncthreads();

    // phase 2: h2 = silu(h1 @ w2 / 8)
    {
        const int e  = t >> 2;
        const int j0 = (t & 3) * 16;
        float acc[16];
#pragma unroll
        for (int j = 0; j < 16; ++j) acc[j] = 0.0f;
        for (int k = 0; k < 64; ++k) {
            float hv = h1s[e * 65 + k];
            const float4 wv0 = *(const float4*)&w2s[k * 64 + j0];
            const float4 wv1 = *(const float4*)&w2s[k * 64 + j0 + 4];
            const float4 wv2 = *(const float4*)&w2s[k * 64 + j0 + 8];
            const float4 wv3 = *(const float4*)&w2s[k * 64 + j0 + 12];
            acc[0]  += hv * wv0.x; acc[1]  += hv * wv0.y; acc[2]  += hv * wv0.z; acc[3]  += hv * wv0.w;
            acc[4]  += hv * wv1.x; acc[5]  += hv * wv1.y; acc[6]  += hv * wv1.z; acc[7]  += hv * wv1.w;
            acc[8]  += hv * wv2.x; acc[9]  += hv * wv2.y; acc[10] += hv * wv2.z; acc[11] += hv * wv2.w;
            acc[12] += hv * wv3.x; acc[13] += hv * wv3.y; acc[14] += hv * wv3.z; acc[15] += hv * wv3.w;
        }
#pragma unroll
        for (int j = 0; j < 16; ++j)
            h2s[e * 65 + j0 + j] = silu_f(acc[j] * 0.125f);
    }

    // phase 3: w = h2 @ w3 * SC3, 3 chunks of 128 cols
    for (int c = 0; c < 3; ++c) {
        __syncthreads();
        for (int i = t; i < 8192; i += 256) {
            int row = i >> 7, col = i & 127;
            w3s[i] = w3[row * 384 + c * 128 + col];
        }
        __syncthreads();

        const int eg = t >> 4;
        const int o0 = (t & 15) * 8;
        float acc[4][8];
#pragma unroll
        for (int i = 0; i < 4; ++i)
#pragma unroll
            for (int j = 0; j < 8; ++j) acc[i][j] = 0.0f;

#pragma unroll 4
        for (int k = 0; k < 64; ++k) {
            const float4 wv0 = *(const float4*)&w3s[k * 128 + o0];
            const float4 wv1 = *(const float4*)&w3s[k * 128 + o0 + 4];
#pragma unroll
            for (int i = 0; i < 4; ++i) {
                float hv = h2s[(eg * 4 + i) * 65 + k];
                acc[i][0] += hv * wv0.x; acc[i][1] += hv * wv0.y;
                acc[i][2] += hv * wv0.z; acc[i][3] += hv * wv0.w;
                acc[i][4] += hv * wv1.x; acc[i][5] += hv * wv1.y;
                acc[i][6] += hv * wv1.z; acc[i][7] += hv * wv1.w;
            }
        }
#pragma unroll
        for (int i = 0; i < 4; ++i) {
            const size_t le = (size_t)(le0 + eg * 4 + i);
            float4 s0, s1;
            s0.x = acc[i][0] * SC3; s0.y = acc[i][1] * SC3;
            s0.z = acc[i][2] * SC3; s0.w = acc[i][3] * SC3;
            s1.x = acc[i][4] * SC3; s1.y = acc[i][5] * SC3;
            s1.z = acc[i][6] * SC3; s1.w = acc[i][7] * SC3;
            *(float4*)&wout[le * 384 + c * 128 + o0]     = s0;
            *(float4*)&wout[le * 384 + c * 128 + o0 + 4] = s1;
        }
    }
}

// ---------------------------------------------------------------------------
// CSR construction: histogram -> scan -> fill permutation
// ---------------------------------------------------------------------------
__global__ __launch_bounds__(256) void hist_kernel(
    const int* __restrict__ receivers, int* __restrict__ counts)
{
    int e = blockIdx.x * 256 + threadIdx.x;
    if (e < N_EDGES) atomicAdd(&counts[receivers[e]], 1);
}

__global__ __launch_bounds__(256) void scan_kernel(
    const int* __restrict__ counts, int* __restrict__ offsets,
    int* __restrict__ cursor)
{
    __shared__ int sums[256];
    __shared__ int excl[256];
    const int t = threadIdx.x;
    const int base = t * 64;                 // 256 * 64 = 16384
    int s = 0;
    for (int i = 0; i < 64; ++i) s += counts[base + i];
    sums[t] = s;
    __syncthreads();
    if (t == 0) {
        int r = 0;
        for (int i = 0; i < 256; ++i) { excl[i] = r; r += sums[i]; }
    }
    __syncthreads();
    int run = excl[t];
    for (int i = 0; i < 64; ++i) {
        offsets[base + i] = run;
        cursor[base + i]  = run;
        run += counts[base + i];
    }
    if (t == 255) offsets[N_NODES] = run;    // == N_EDGES
}

__global__ __launch_bounds__(256) void fill_kernel(
    const int* __restrict__ receivers, int* __restrict__ cursor,
    int* __restrict__ sorted)
{
    int e = blockIdx.x * 256 + threadIdx.x;
    if (e < N_EDGES) {
        int pos = atomicAdd(&cursor[receivers[e]], 1);
        sorted[pos] = e;
    }
}

// ---------------------------------------------------------------------------
// Kernel 2: per-node accumulation (atomic-free). One block per node, 4 waves;
// lane = channel. Each wave accumulates a strided subset of the node's edges
// in registers; LDS reduction across waves; one coalesced row write.
// ---------------------------------------------------------------------------
__global__ __launch_bounds__(256) void accum_kernel(
    const float* __restrict__ node_feats,     // (N, 256)
    const float* __restrict__ edge_features,  // (E, 4)
    const float* __restrict__ wbuf,           // (chunk, 384), local-chunk indexed
    const int* __restrict__ senders,
    const int* __restrict__ sorted,           // (E,) edge ids grouped by receiver
    const int* __restrict__ offsets,          // (N+1,)
    float* __restrict__ out,                  // (N, 768)
    int e0, int cnt)
{
    const int n    = blockIdx.x;
    const int wid  = threadIdx.x >> 6;
    const int lane = threadIdx.x & 63;
    const int beg  = offsets[n];
    const int end  = offsets[n + 1];

    float as0 = 0.f, as1 = 0.f, as2 = 0.f;
    float av[3][3] = {};   // [which vec output][xyz]

    for (int i = beg + wid; i < end; i += 4) {
        const int e = sorted[i];
        if (e < e0 || e >= e0 + cnt) continue;   // outside this wbuf chunk

        const int sidx  = senders[e];
        const float es  = edge_features[e * 4 + 0];
        const float ev0 = edge_features[e * 4 + 1];
        const float ev1 = edge_features[e * 4 + 2];
        const float ev2 = edge_features[e * 4 + 3];

        const float* nf = node_feats + (size_t)sidx * 256;
        const float s  = nf[lane];
        const float v0 = nf[64 + lane * 3 + 0];
        const float v1 = nf[64 + lane * 3 + 1];
        const float v2 = nf[64 + lane * 3 + 2];

        const float* wp = wbuf + (size_t)(e - e0) * 384;
        const float ws0 = wp[lane];
        const float ws1 = wp[64 + lane];
        const float ws2 = wp[128 + lane];
        const float wv0 = wp[192 + lane];
        const float wv1 = wp[256 + lane];
        const float wv2 = wp[320 + lane];

        const float dot = (v0 * ev0 + v1 * ev1 + v2 * ev2) * INV_SQRT3;

        as0 += s * ws0;
        as1 += s * es * ws1;
        as2 += dot * ws2;

        av[0][0] += v0 * wv0; av[0][1] += v1 * wv0; av[0][2] += v2 * wv0;
        const float sw = s * wv1;
        av[1][0] += ev0 * sw; av[1][1] += ev1 * sw; av[1][2] += ev2 * sw;
        const float esw = es * wv2;
        av[2][0] += v0 * esw; av[2][1] += v1 * esw; av[2][2] += v2 * esw;
    }

    __shared__ float red[4 * 768];
    float* my = red + wid * 768;
    my[lane]        = as0;
    my[64 + lane]   = as1;
    my[128 + lane]  = as2;
#pragma unroll
    for (int c = 0; c < 3; ++c) {
        const int b = 192 + (c * 64 + lane) * 3;
        my[b + 0] = av[c][0];
        my[b + 1] = av[c][1];
        my[b + 2] = av[c][2];
    }
    __syncthreads();

    float* orow = out + (size_t)n * 768;
    for (int j = threadIdx.x; j < 768; j += 256) {
        float v = red[j] + red[768 + j] + red[1536 + j] + red[2304 + j];
        if (e0 == 0) orow[j] = v;           // first chunk initializes
        else         orow[j] += v;          // later chunks accumulate (block owns row)
    }
}

// ---------------------------------------------------------------------------
extern "C" void kernel_launch(void* const* d_in, const int* in_sizes, int n_in,
                              void* d_out, int out_size, void* d_ws, size_t ws_size,
                              hipStream_t stream) {
    const float* node_feats    = (const float*)d_in[0];
    const float* edge_features = (const float*)d_in[1];
    const float* radial        = (const float*)d_in[2];
    const float* w1            = (const float*)d_in[3];
    const float* w2            = (const float*)d_in[4];
    const float* w3            = (const float*)d_in[5];
    const int*   senders       = (const int*)d_in[6];
    const int*   receivers     = (const int*)d_in[7];
    float* out = (float*)d_out;

    // Workspace layout: [counts N][offsets N+1][cursor N][sorted E][wbuf ...]
    int* counts  = (int*)d_ws;
    int* offsets = counts + N_NODES;
    int* cursor  = offsets + N_NODES + 1;
    int* sorted  = cursor + N_NODES;
    size_t int_bytes = (size_t)((char*)(sorted + N_EDGES) - (char*)d_ws);
    size_t wbuf_off  = (int_bytes + 255) & ~(size_t)255;      // 16B+ align for float4
    float* wbuf = (float*)((char*)d_ws + wbuf_off);

    // Build receiver-CSR (counts poisoned 0xAA each call -> zero first).
    hipMemsetAsync(counts, 0, (size_t)N_NODES * sizeof(int), stream);
    hist_kernel<<<(N_EDGES + 255) / 256, 256, 0, stream>>>(receivers, counts);
    scan_kernel<<<1, 256, 0, stream>>>(counts, offsets, cursor);
    fill_kernel<<<(N_EDGES + 255) / 256, 256, 0, stream>>>(receivers, cursor, sorted);

    // Chunk edges through remaining workspace (w = chunk x 384 fp32).
    size_t avail = (ws_size > wbuf_off) ? (ws_size - wbuf_off) : 0;
    size_t max_chunk = avail / (NUM_IRREPS * sizeof(float));
    max_chunk &= ~(size_t)(TE - 1);
    int chunk = (max_chunk >= (size_t)N_EDGES) ? N_EDGES
              : (max_chunk < (size_t)TE ? TE : (int)max_chunk);

    for (int e0 = 0; e0 < N_EDGES; e0 += chunk) {
        int cnt = N_EDGES - e0;
        if (cnt > chunk) cnt = chunk;
        int nb1 = (cnt + TE - 1) / TE;
        mlp_kernel<<<nb1, 256, 0, stream>>>(radial, w1, w2, w3, wbuf, e0);
        accum_kernel<<<N_NODES, 256, 0, stream>>>(node_feats, edge_features, wbuf,
                                                  senders, sorted, offsets, out, e0, cnt);
    }
}

// Round 3
// 235.072 us; speedup vs baseline: 4.3874x; 1.2828x over previous
//
#include <hip/hip_runtime.h>

#define N_NODES 16384
#define N_EDGES 131072
#define MUL 64
#define HIDDEN 64
#define NUM_IRREPS 384      // 6*MUL
#define TE 64               // edges per block in MLP kernel

#define INV_SQRT3   0.5773502691896258f
#define INV_SQRT8   0.35355339059327373f   // 1/sqrt(N_RADIAL)
#define SC3         (0.125f * 0.35355339059327373f)  // (1/sqrt(HIDDEN)) * (1/sqrt(avg_neighbors))

typedef __attribute__((ext_vector_type(8))) __bf16 bf16x8;
typedef __attribute__((ext_vector_type(8))) unsigned short ushort8;
typedef __attribute__((ext_vector_type(4))) float f32x4;

union FragU { ushort8 u; bf16x8 b; };

__device__ __forceinline__ float silu_f(float x) {
    return x / (1.0f + __expf(-x));
}
__device__ __forceinline__ unsigned short bf16_rn(float f) {
    union { float f; unsigned int u; } c; c.f = f;
    unsigned int u = c.u + 0x7FFFu + ((c.u >> 16) & 1u);
    return (unsigned short)(u >> 16);
}
__device__ __forceinline__ float bf16_to_f(unsigned short h) {
    union { unsigned int u; float f; } c; c.u = ((unsigned int)h) << 16;
    return c.f;
}

// ---------------------------------------------------------------------------
// Pack w2 (scale 1/8) and w3 (scale SC3) into MFMA B-fragment order, split
// into bf16 hi/lo planes. Layout: plane-major [hi | lo], within a plane:
// idx = K*(tiles*512) + T*512 + lane*8 + j  holds  W[K*32 + (lane>>4)*8 + j][T*16 + (lane&15)]
// w2p: 2 planes x 4096 shorts; w3p: 2 planes x 24576 shorts.
// ---------------------------------------------------------------------------
__global__ __launch_bounds__(256) void pack_kernel(
    const float* __restrict__ w2, const float* __restrict__ w3,
    unsigned short* __restrict__ w2p, unsigned short* __restrict__ w3p)
{
    int t = blockIdx.x * 256 + threadIdx.x;
    float v;
    unsigned short *hi_dst, *lo_dst;
    if (t < 4096) {
        int K = t >> 11, T = (t >> 9) & 3, lane = (t >> 3) & 63, j = t & 7;
        int k = K * 32 + (lane >> 4) * 8 + j;
        int n = T * 16 + (lane & 15);
        v = w2[k * 64 + n] * 0.125f;
        hi_dst = w2p + t; lo_dst = w2p + 4096 + t;
    } else if (t < 28672) {
        int u = t - 4096;
        int K = u / 12288; int rem = u - K * 12288;
        int T = rem >> 9, lane = (rem >> 3) & 63, j = rem & 7;
        int k = K * 32 + (lane >> 4) * 8 + j;
        int n = T * 16 + (lane & 15);
        v = w3[k * 384 + n] * SC3;
        hi_dst = w3p + u; lo_dst = w3p + 24576 + u;
    } else {
        return;
    }
    unsigned short h = bf16_rn(v);
    unsigned short l = bf16_rn(v - bf16_to_f(h));
    *hi_dst = h; *lo_dst = l;
}

// ---------------------------------------------------------------------------
// Kernel 1: per-edge radial MLP -> w[e][384]. Phase 1 (tiny GEMM K=8) in
// VALU; GEMM2/GEMM3 via bf16x3 MFMA (hi*hi + hi*lo + lo*hi, fp32 accum).
// Each wave owns one 16-edge M-tile; B-frags streamed from L2-resident
// packed weights (no LDS for B).
// ---------------------------------------------------------------------------
__global__ __launch_bounds__(256) void mlp_kernel(
    const float* __restrict__ radial,            // (E, 8)
    const float* __restrict__ w1,                // (8, 64)
    const unsigned short* __restrict__ w2p,      // packed
    const unsigned short* __restrict__ w3p,      // packed
    float* __restrict__ wout,                    // (chunk, 384)
    int e_begin)
{
    __shared__ float w1s[512];
    __shared__ float rs[64 * 9];
    __shared__ float h1s[64 * 68];   // stride 68: 16B-aligned rows for b128
    __shared__ float h2s[64 * 68];

    const int t   = threadIdx.x;
    const int le0 = blockIdx.x * TE;
    const int e0  = e_begin + le0;

    for (int i = t; i < 512; i += 256) w1s[i] = w1[i];
    for (int i = t; i < 512; i += 256)
        rs[(i >> 3) * 9 + (i & 7)] = radial[(size_t)e0 * 8 + i];
    __syncthreads();

    // ---- phase 1: h1 = silu(r @ w1 / sqrt(8)), VALU ----
    {
        const int e  = t >> 2;
        const int j0 = (t & 3) * 16;
        float acc[16];
#pragma unroll
        for (int j = 0; j < 16; ++j) acc[j] = 0.0f;
#pragma unroll
        for (int k = 0; k < 8; ++k) {
            float rv = rs[e * 9 + k];
#pragma unroll
            for (int j = 0; j < 16; ++j)
                acc[j] += rv * w1s[k * 64 + j0 + j];
        }
#pragma unroll
        for (int j = 0; j < 16; ++j)
            h1s[e * 68 + j0 + j] = silu_f(acc[j] * INV_SQRT8);
    }
    __syncthreads();

    const int lane = t & 63;
    const int wv   = t >> 6;        // wave id == M-tile
    const int m0   = wv * 16;
    const int quad = lane >> 4;
    const int l15  = lane & 15;

    FragU ah[2], al[2];

    // ---- build A-frags from h1s, split hi/lo ----
#pragma unroll
    for (int K = 0; K < 2; ++K) {
        const float4* p = (const float4*)&h1s[(m0 + l15) * 68 + K * 32 + quad * 8];
        float4 x0 = p[0], x1 = p[1];
        float xs[8] = {x0.x, x0.y, x0.z, x0.w, x1.x, x1.y, x1.z, x1.w};
#pragma unroll
        for (int j = 0; j < 8; ++j) {
            unsigned short h = bf16_rn(xs[j]);
            ah[K].u[j] = h;
            al[K].u[j] = bf16_rn(xs[j] - bf16_to_f(h));
        }
    }

    // ---- phase 2: h2 = silu(h1 @ w2p) via MFMA, 4 N-tiles ----
#pragma unroll
    for (int T = 0; T < 4; ++T) {
        FragU bh0, bh1, bl0, bl1;
        bh0.u = *(const ushort8*)(w2p +        T * 512 + lane * 8);
        bh1.u = *(const ushort8*)(w2p + 2048 + T * 512 + lane * 8);
        bl0.u = *(const ushort8*)(w2p + 4096 + T * 512 + lane * 8);
        bl1.u = *(const ushort8*)(w2p + 6144 + T * 512 + lane * 8);
        f32x4 acc = {0.f, 0.f, 0.f, 0.f};
        acc = __builtin_amdgcn_mfma_f32_16x16x32_bf16(ah[0].b, bh0.b, acc, 0, 0, 0);
        acc = __builtin_amdgcn_mfma_f32_16x16x32_bf16(ah[1].b, bh1.b, acc, 0, 0, 0);
        acc = __builtin_amdgcn_mfma_f32_16x16x32_bf16(ah[0].b, bl0.b, acc, 0, 0, 0);
        acc = __builtin_amdgcn_mfma_f32_16x16x32_bf16(ah[1].b, bl1.b, acc, 0, 0, 0);
        acc = __builtin_amdgcn_mfma_f32_16x16x32_bf16(al[0].b, bh0.b, acc, 0, 0, 0);
        acc = __builtin_amdgcn_mfma_f32_16x16x32_bf16(al[1].b, bh1.b, acc, 0, 0, 0);
#pragma unroll
        for (int r = 0; r < 4; ++r)
            h2s[(m0 + quad * 4 + r) * 68 + T * 16 + l15] = silu_f(acc[r]);
    }
    __syncthreads();

    // ---- build A-frags from h2s ----
#pragma unroll
    for (int K = 0; K < 2; ++K) {
        const float4* p = (const float4*)&h2s[(m0 + l15) * 68 + K * 32 + quad * 8];
        float4 x0 = p[0], x1 = p[1];
        float xs[8] = {x0.x, x0.y, x0.z, x0.w, x1.x, x1.y, x1.z, x1.w};
#pragma unroll
        for (int j = 0; j < 8; ++j) {
            unsigned short h = bf16_rn(xs[j]);
            ah[K].u[j] = h;
            al[K].u[j] = bf16_rn(xs[j] - bf16_to_f(h));
        }
    }

    // ---- phase 3: w = h2 @ w3p via MFMA, 24 N-tiles, store to wout ----
    for (int T = 0; T < 24; ++T) {
        FragU bh0, bh1, bl0, bl1;
        bh0.u = *(const ushort8*)(w3p +         T * 512 + lane * 8);
        bh1.u = *(const ushort8*)(w3p + 12288 + T * 512 + lane * 8);
        bl0.u = *(const ushort8*)(w3p + 24576 + T * 512 + lane * 8);
        bl1.u = *(const ushort8*)(w3p + 36864 + T * 512 + lane * 8);
        f32x4 acc = {0.f, 0.f, 0.f, 0.f};
        acc = __builtin_amdgcn_mfma_f32_16x16x32_bf16(ah[0].b, bh0.b, acc, 0, 0, 0);
        acc = __builtin_amdgcn_mfma_f32_16x16x32_bf16(ah[1].b, bh1.b, acc, 0, 0, 0);
        acc = __builtin_amdgcn_mfma_f32_16x16x32_bf16(ah[0].b, bl0.b, acc, 0, 0, 0);
        acc = __builtin_amdgcn_mfma_f32_16x16x32_bf16(ah[1].b, bl1.b, acc, 0, 0, 0);
        acc = __builtin_amdgcn_mfma_f32_16x16x32_bf16(al[0].b, bh0.b, acc, 0, 0, 0);
        acc = __builtin_amdgcn_mfma_f32_16x16x32_bf16(al[1].b, bh1.b, acc, 0, 0, 0);
#pragma unroll
        for (int r = 0; r < 4; ++r)
            wout[(size_t)(le0 + m0 + quad * 4 + r) * 384 + T * 16 + l15] = acc[r];
    }
}

// ---------------------------------------------------------------------------
// CSR construction: histogram -> scan -> fill permutation
// ---------------------------------------------------------------------------
__global__ __launch_bounds__(256) void hist_kernel(
    const int* __restrict__ receivers, int* __restrict__ counts)
{
    int e = blockIdx.x * 256 + threadIdx.x;
    if (e < N_EDGES) atomicAdd(&counts[receivers[e]], 1);
}

__global__ __launch_bounds__(256) void scan_kernel(
    const int* __restrict__ counts, int* __restrict__ offsets,
    int* __restrict__ cursor)
{
    __shared__ int sums[256];
    __shared__ int excl[256];
    const int t = threadIdx.x;
    const int base = t * 64;
    int s = 0;
    for (int i = 0; i < 64; ++i) s += counts[base + i];
    sums[t] = s;
    __syncthreads();
    if (t == 0) {
        int r = 0;
        for (int i = 0; i < 256; ++i) { excl[i] = r; r += sums[i]; }
    }
    __syncthreads();
    int run = excl[t];
    for (int i = 0; i < 64; ++i) {
        offsets[base + i] = run;
        cursor[base + i]  = run;
        run += counts[base + i];
    }
    if (t == 255) offsets[N_NODES] = run;
}

__global__ __launch_bounds__(256) void fill_kernel(
    const int* __restrict__ receivers, int* __restrict__ cursor,
    int* __restrict__ sorted)
{
    int e = blockIdx.x * 256 + threadIdx.x;
    if (e < N_EDGES) {
        int pos = atomicAdd(&cursor[receivers[e]], 1);
        sorted[pos] = e;
    }
}

// ---------------------------------------------------------------------------
// Kernel 2: per-node accumulation (atomic-free). One block per node, 4 waves;
// lane = channel.
// ---------------------------------------------------------------------------
__global__ __launch_bounds__(256) void accum_kernel(
    const float* __restrict__ node_feats,     // (N, 256)
    const float* __restrict__ edge_features,  // (E, 4)
    const float* __restrict__ wbuf,           // (chunk, 384)
    const int* __restrict__ senders,
    const int* __restrict__ sorted,
    const int* __restrict__ offsets,
    float* __restrict__ out,                  // (N, 768)
    int e0, int cnt)
{
    const int n    = blockIdx.x;
    const int wid  = threadIdx.x >> 6;
    const int lane = threadIdx.x & 63;
    const int beg  = offsets[n];
    const int end  = offsets[n + 1];

    float as0 = 0.f, as1 = 0.f, as2 = 0.f;
    float av[3][3] = {};

    for (int i = beg + wid; i < end; i += 4) {
        const int e = sorted[i];
        if (e < e0 || e >= e0 + cnt) continue;

        const int sidx  = senders[e];
        const float es  = edge_features[e * 4 + 0];
        const float ev0 = edge_features[e * 4 + 1];
        const float ev1 = edge_features[e * 4 + 2];
        const float ev2 = edge_features[e * 4 + 3];

        const float* nf = node_feats + (size_t)sidx * 256;
        const float s  = nf[lane];
        const float v0 = nf[64 + lane * 3 + 0];
        const float v1 = nf[64 + lane * 3 + 1];
        const float v2 = nf[64 + lane * 3 + 2];

        const float* wp = wbuf + (size_t)(e - e0) * 384;
        const float ws0 = wp[lane];
        const float ws1 = wp[64 + lane];
        const float ws2 = wp[128 + lane];
        const float wv0 = wp[192 + lane];
        const float wv1 = wp[256 + lane];
        const float wv2 = wp[320 + lane];

        const float dot = (v0 * ev0 + v1 * ev1 + v2 * ev2) * INV_SQRT3;

        as0 += s * ws0;
        as1 += s * es * ws1;
        as2 += dot * ws2;

        av[0][0] += v0 * wv0; av[0][1] += v1 * wv0; av[0][2] += v2 * wv0;
        const float sw = s * wv1;
        av[1][0] += ev0 * sw; av[1][1] += ev1 * sw; av[1][2] += ev2 * sw;
        const float esw = es * wv2;
        av[2][0] += v0 * esw; av[2][1] += v1 * esw; av[2][2] += v2 * esw;
    }

    __shared__ float red[4 * 768];
    float* my = red + wid * 768;
    my[lane]        = as0;
    my[64 + lane]   = as1;
    my[128 + lane]  = as2;
#pragma unroll
    for (int c = 0; c < 3; ++c) {
        const int b = 192 + (c * 64 + lane) * 3;
        my[b + 0] = av[c][0];
        my[b + 1] = av[c][1];
        my[b + 2] = av[c][2];
    }
    __syncthreads();

    float* orow = out + (size_t)n * 768;
    for (int j = threadIdx.x; j < 768; j += 256) {
        float v = red[j] + red[768 + j] + red[1536 + j] + red[2304 + j];
        if (e0 == 0) orow[j] = v;
        else         orow[j] += v;
    }
}

// ---------------------------------------------------------------------------
extern "C" void kernel_launch(void* const* d_in, const int* in_sizes, int n_in,
                              void* d_out, int out_size, void* d_ws, size_t ws_size,
                              hipStream_t stream) {
    const float* node_feats    = (const float*)d_in[0];
    const float* edge_features = (const float*)d_in[1];
    const float* radial        = (const float*)d_in[2];
    const float* w1            = (const float*)d_in[3];
    const float* w2            = (const float*)d_in[4];
    const float* w3            = (const float*)d_in[5];
    const int*   senders       = (const int*)d_in[6];
    const int*   receivers     = (const int*)d_in[7];
    float* out = (float*)d_out;

    // ws layout: [counts N][offsets N+1][cursor N][sorted E] | [w2p 8192][w3p 49152] | [wbuf]
    int* counts  = (int*)d_ws;
    int* offsets = counts + N_NODES;
    int* cursor  = offsets + N_NODES + 1;
    int* sorted  = cursor + N_NODES;
    size_t int_bytes = (size_t)((char*)(sorted + N_EDGES) - (char*)d_ws);
    size_t pk_off = (int_bytes + 255) & ~(size_t)255;
    unsigned short* w2p = (unsigned short*)((char*)d_ws + pk_off);
    unsigned short* w3p = w2p + 8192;
    size_t wbuf_off = (pk_off + (8192 + 49152) * sizeof(unsigned short) + 255) & ~(size_t)255;
    float* wbuf = (float*)((char*)d_ws + wbuf_off);

    hipMemsetAsync(counts, 0, (size_t)N_NODES * sizeof(int), stream);
    hist_kernel<<<(N_EDGES + 255) / 256, 256, 0, stream>>>(receivers, counts);
    scan_kernel<<<1, 256, 0, stream>>>(counts, offsets, cursor);
    fill_kernel<<<(N_EDGES + 255) / 256, 256, 0, stream>>>(receivers, cursor, sorted);
    pack_kernel<<<112, 256, 0, stream>>>(w2, w3, w2p, w3p);

    size_t avail = (ws_size > wbuf_off) ? (ws_size - wbuf_off) : 0;
    size_t max_chunk = avail / (NUM_IRREPS * sizeof(float));
    max_chunk &= ~(size_t)(TE - 1);
    int chunk = (max_chunk >= (size_t)N_EDGES) ? N_EDGES
              : (max_chunk < (size_t)TE ? TE : (int)max_chunk);

    for (int e0 = 0; e0 < N_EDGES; e0 += chunk) {
        int cnt = N_EDGES - e0;
        if (cnt > chunk) cnt = chunk;
        int nb1 = (cnt + TE - 1) / TE;
        mlp_kernel<<<nb1, 256, 0, stream>>>(radial, w1, w2p, w3p, wbuf, e0);
        accum_kernel<<<N_NODES, 256, 0, stream>>>(node_feats, edge_features, wbuf,
                                                  senders, sorted, offsets, out, e0, cnt);
    }
}

// Round 6
// 202.557 us; speedup vs baseline: 5.0917x; 1.1605x over previous
//
#include <hip/hip_runtime.h>

#define N_NODES 16384
#define N_EDGES 131072
#define NUM_IRREPS 384      // 6*MUL
#define TE 64               // edges per block in MLP kernel

#define INV_SQRT3   0.5773502691896258f
#define INV_SQRT8   0.35355339059327373f   // 1/sqrt(N_RADIAL)
#define SC3         (0.125f * 0.35355339059327373f)  // (1/sqrt(HIDDEN)) * (1/sqrt(avg_neighbors))

typedef __attribute__((ext_vector_type(8))) __bf16 bf16x8;
typedef __attribute__((ext_vector_type(8))) unsigned short ushort8;
typedef __attribute__((ext_vector_type(4))) float f32x4;

union FragU { ushort8 u; bf16x8 b; };

__device__ __forceinline__ float silu_f(float x) {
    return x / (1.0f + __expf(-x));
}
__device__ __forceinline__ unsigned short bf16_rn(float f) {
    union { float f; unsigned int u; } c; c.f = f;
    unsigned int u = c.u + 0x7FFFu + ((c.u >> 16) & 1u);
    return (unsigned short)(u >> 16);
}
__device__ __forceinline__ float bf16_to_f(unsigned short h) {
    union { unsigned int u; float f; } c; c.u = ((unsigned int)h) << 16;
    return c.f;
}

// ---------------------------------------------------------------------------
// Pack w2 (scale 1/8) and w3 (scale SC3) into MFMA B-fragment order, split
// into bf16 hi/lo planes (verified R3 layout).
// ---------------------------------------------------------------------------
__global__ __launch_bounds__(256) void pack_kernel(
    const float* __restrict__ w2, const float* __restrict__ w3,
    unsigned short* __restrict__ w2p, unsigned short* __restrict__ w3p)
{
    int t = blockIdx.x * 256 + threadIdx.x;
    float v;
    unsigned short *hi_dst, *lo_dst;
    if (t < 4096) {
        int K = t >> 11, T = (t >> 9) & 3, lane = (t >> 3) & 63, j = t & 7;
        int k = K * 32 + (lane >> 4) * 8 + j;
        int n = T * 16 + (lane & 15);
        v = w2[k * 64 + n] * 0.125f;
        hi_dst = w2p + t; lo_dst = w2p + 4096 + t;
    } else if (t < 28672) {
        int u = t - 4096;
        int K = u / 12288; int rem = u - K * 12288;
        int T = rem >> 9, lane = (rem >> 3) & 63, j = rem & 7;
        int k = K * 32 + (lane >> 4) * 8 + j;
        int n = T * 16 + (lane & 15);
        v = w3[k * 384 + n] * SC3;
        hi_dst = w3p + u; lo_dst = w3p + 24576 + u;
    } else {
        return;
    }
    unsigned short h = bf16_rn(v);
    unsigned short l = bf16_rn(v - bf16_to_f(h));
    *hi_dst = h; *lo_dst = l;
}

// ---------------------------------------------------------------------------
// CSR construction: histogram -> scan -> fill permutation
// ---------------------------------------------------------------------------
__global__ __launch_bounds__(256) void hist_kernel(
    const int* __restrict__ receivers, int* __restrict__ counts)
{
    int e = blockIdx.x * 256 + threadIdx.x;
    if (e < N_EDGES) atomicAdd(&counts[receivers[e]], 1);
}

__global__ __launch_bounds__(256) void scan_kernel(
    const int* __restrict__ counts, int* __restrict__ offsets,
    int* __restrict__ cursor)
{
    __shared__ int sums[256];
    __shared__ int excl[256];
    const int t = threadIdx.x;
    const int base = t * 64;
    int s = 0;
    for (int i = 0; i < 64; ++i) s += counts[base + i];
    sums[t] = s;
    __syncthreads();
    if (t == 0) {
        int r = 0;
        for (int i = 0; i < 256; ++i) { excl[i] = r; r += sums[i]; }
    }
    __syncthreads();
    int run = excl[t];
    for (int i = 0; i < 64; ++i) {
        offsets[base + i] = run;
        cursor[base + i]  = run;
        run += counts[base + i];
    }
    if (t == 255) offsets[N_NODES] = run;
}

__global__ __launch_bounds__(256) void fill_kernel(
    const int* __restrict__ receivers, int* __restrict__ cursor,
    int* __restrict__ sorted)
{
    int e = blockIdx.x * 256 + threadIdx.x;
    if (e < N_EDGES) {
        int pos = atomicAdd(&cursor[receivers[e]], 1);
        sorted[pos] = e;
    }
}

// ---------------------------------------------------------------------------
// Kernel 1: radial MLP over 64 sorted positions per block; output row i of
// wout = w(edge sorted[p_begin + i]) in bf16. R3-verified MFMA core; the only
// new front-end logic is the radial gather by sorted edge id.
// ---------------------------------------------------------------------------
__global__ __launch_bounds__(256) void mlp_kernel(
    const float* __restrict__ radial,            // (E, 8)
    const float* __restrict__ w1,                // (8, 64)
    const unsigned short* __restrict__ w2p,      // packed hi/lo
    const unsigned short* __restrict__ w3p,      // packed hi/lo
    const int* __restrict__ sorted,              // (E,)
    unsigned short* __restrict__ wout,           // (chunk, 384) bf16, sorted order
    int p_begin)
{
    __shared__ float w1s[512];
    __shared__ float rs[64 * 9];
    __shared__ float h1s[64 * 68];   // stride 68: 16B-aligned rows
    __shared__ float h2s[64 * 68];

    const int t   = threadIdx.x;
    const int le0 = blockIdx.x * TE;
    const int p0  = p_begin + le0;   // global sorted-position base

    for (int i = t; i < 512; i += 256) w1s[i] = w1[i];
    if (t < 128) {
        int j = t >> 1, half = t & 1;
        int eid = sorted[p0 + j];
        float4 rv = *(const float4*)&radial[(size_t)eid * 8 + half * 4];
        float* d = &rs[j * 9 + half * 4];
        d[0] = rv.x; d[1] = rv.y; d[2] = rv.z; d[3] = rv.w;
    }
    __syncthreads();

    // ---- phase 1: h1 = silu(r @ w1 / sqrt(8)), VALU ----
    {
        const int e  = t >> 2;
        const int j0 = (t & 3) * 16;
        float acc[16];
#pragma unroll
        for (int j = 0; j < 16; ++j) acc[j] = 0.0f;
#pragma unroll
        for (int k = 0; k < 8; ++k) {
            float rv = rs[e * 9 + k];
#pragma unroll
            for (int j = 0; j < 16; ++j)
                acc[j] += rv * w1s[k * 64 + j0 + j];
        }
#pragma unroll
        for (int j = 0; j < 16; ++j)
            h1s[e * 68 + j0 + j] = silu_f(acc[j] * INV_SQRT8);
    }
    __syncthreads();

    const int lane = t & 63;
    const int wv   = t >> 6;        // wave id == M-tile
    const int m0   = wv * 16;
    const int quad = lane >> 4;
    const int l15  = lane & 15;

    FragU ah[2], al[2];

    // ---- A-frags from h1, hi/lo split ----
#pragma unroll
    for (int K = 0; K < 2; ++K) {
        const float4* p = (const float4*)&h1s[(m0 + l15) * 68 + K * 32 + quad * 8];
        float4 x0 = p[0], x1 = p[1];
        float xs[8] = {x0.x, x0.y, x0.z, x0.w, x1.x, x1.y, x1.z, x1.w};
#pragma unroll
        for (int j = 0; j < 8; ++j) {
            unsigned short h = bf16_rn(xs[j]);
            ah[K].u[j] = h;
            al[K].u[j] = bf16_rn(xs[j] - bf16_to_f(h));
        }
    }

    // ---- phase 2: h2 = silu(h1 @ w2p) via MFMA ----
#pragma unroll
    for (int T = 0; T < 4; ++T) {
        FragU bh0, bh1, bl0, bl1;
        bh0.u = *(const ushort8*)(w2p +        T * 512 + lane * 8);
        bh1.u = *(const ushort8*)(w2p + 2048 + T * 512 + lane * 8);
        bl0.u = *(const ushort8*)(w2p + 4096 + T * 512 + lane * 8);
        bl1.u = *(const ushort8*)(w2p + 6144 + T * 512 + lane * 8);
        f32x4 acc = {0.f, 0.f, 0.f, 0.f};
        acc = __builtin_amdgcn_mfma_f32_16x16x32_bf16(ah[0].b, bh0.b, acc, 0, 0, 0);
        acc = __builtin_amdgcn_mfma_f32_16x16x32_bf16(ah[1].b, bh1.b, acc, 0, 0, 0);
        acc = __builtin_amdgcn_mfma_f32_16x16x32_bf16(ah[0].b, bl0.b, acc, 0, 0, 0);
        acc = __builtin_amdgcn_mfma_f32_16x16x32_bf16(ah[1].b, bl1.b, acc, 0, 0, 0);
        acc = __builtin_amdgcn_mfma_f32_16x16x32_bf16(al[0].b, bh0.b, acc, 0, 0, 0);
        acc = __builtin_amdgcn_mfma_f32_16x16x32_bf16(al[1].b, bh1.b, acc, 0, 0, 0);
#pragma unroll
        for (int r = 0; r < 4; ++r)
            h2s[(m0 + quad * 4 + r) * 68 + T * 16 + l15] = silu_f(acc[r]);
    }
    __syncthreads();

    // ---- A-frags from h2 ----
#pragma unroll
    for (int K = 0; K < 2; ++K) {
        const float4* p = (const float4*)&h2s[(m0 + l15) * 68 + K * 32 + quad * 8];
        float4 x0 = p[0], x1 = p[1];
        float xs[8] = {x0.x, x0.y, x0.z, x0.w, x1.x, x1.y, x1.z, x1.w};
#pragma unroll
        for (int j = 0; j < 8; ++j) {
            unsigned short h = bf16_rn(xs[j]);
            ah[K].u[j] = h;
            al[K].u[j] = bf16_rn(xs[j] - bf16_to_f(h));
        }
    }

    // ---- phase 3: w = h2 @ w3p via MFMA -> wout (bf16, global, sorted order) ----
    for (int T = 0; T < 24; ++T) {
        FragU bh0, bh1, bl0, bl1;
        bh0.u = *(const ushort8*)(w3p +         T * 512 + lane * 8);
        bh1.u = *(const ushort8*)(w3p + 12288 + T * 512 + lane * 8);
        bl0.u = *(const ushort8*)(w3p + 24576 + T * 512 + lane * 8);
        bl1.u = *(const ushort8*)(w3p + 36864 + T * 512 + lane * 8);
        f32x4 acc = {0.f, 0.f, 0.f, 0.f};
        acc = __builtin_amdgcn_mfma_f32_16x16x32_bf16(ah[0].b, bh0.b, acc, 0, 0, 0);
        acc = __builtin_amdgcn_mfma_f32_16x16x32_bf16(ah[1].b, bh1.b, acc, 0, 0, 0);
        acc = __builtin_amdgcn_mfma_f32_16x16x32_bf16(ah[0].b, bl0.b, acc, 0, 0, 0);
        acc = __builtin_amdgcn_mfma_f32_16x16x32_bf16(ah[1].b, bl1.b, acc, 0, 0, 0);
        acc = __builtin_amdgcn_mfma_f32_16x16x32_bf16(al[0].b, bh0.b, acc, 0, 0, 0);
        acc = __builtin_amdgcn_mfma_f32_16x16x32_bf16(al[1].b, bh1.b, acc, 0, 0, 0);
#pragma unroll
        for (int r = 0; r < 4; ++r)
            wout[(size_t)(le0 + m0 + quad * 4 + r) * 384 + T * 16 + l15] = bf16_rn(acc[r]);
    }
}

// ---------------------------------------------------------------------------
// Kernel 2: per-node accumulation (atomic-free). One block per node, 4 waves;
// lane = channel. wbuf is bf16 in receiver-sorted order (row = position).
// ---------------------------------------------------------------------------
__global__ __launch_bounds__(256) void accum_kernel(
    const float* __restrict__ node_feats,        // (N, 256)
    const float* __restrict__ edge_features,     // (E, 4)
    const unsigned short* __restrict__ wbuf,     // (chunk, 384) bf16, sorted order
    const int* __restrict__ senders,
    const int* __restrict__ sorted,
    const int* __restrict__ offsets,
    float* __restrict__ out,                     // (N, 768)
    int p0, int cnt)
{
    const int n    = blockIdx.x;
    const int wid  = threadIdx.x >> 6;
    const int lane = threadIdx.x & 63;
    const int beg  = offsets[n];
    const int end  = offsets[n + 1];

    float as0 = 0.f, as1 = 0.f, as2 = 0.f;
    float av[3][3] = {};

    for (int i = beg + wid; i < end; i += 4) {
        if (i < p0 || i >= p0 + cnt) continue;   // outside this wbuf chunk

        const int e     = sorted[i];
        const int sidx  = senders[e];
        const float es  = edge_features[e * 4 + 0];
        const float ev0 = edge_features[e * 4 + 1];
        const float ev1 = edge_features[e * 4 + 2];
        const float ev2 = edge_features[e * 4 + 3];

        const float* nf = node_feats + (size_t)sidx * 256;
        const float s  = nf[lane];
        const float v0 = nf[64 + lane * 3 + 0];
        const float v1 = nf[64 + lane * 3 + 1];
        const float v2 = nf[64 + lane * 3 + 2];

        const unsigned short* wp = wbuf + (size_t)(i - p0) * 384;
        const float ws0 = bf16_to_f(wp[lane]);
        const float ws1 = bf16_to_f(wp[64 + lane]);
        const float ws2 = bf16_to_f(wp[128 + lane]);
        const float wv0 = bf16_to_f(wp[192 + lane]);
        const float wv1 = bf16_to_f(wp[256 + lane]);
        const float wv2 = bf16_to_f(wp[320 + lane]);

        const float dot = (v0 * ev0 + v1 * ev1 + v2 * ev2) * INV_SQRT3;

        as0 += s * ws0;
        as1 += s * es * ws1;
        as2 += dot * ws2;

        av[0][0] += v0 * wv0; av[0][1] += v1 * wv0; av[0][2] += v2 * wv0;
        const float sw = s * wv1;
        av[1][0] += ev0 * sw; av[1][1] += ev1 * sw; av[1][2] += ev2 * sw;
        const float esw = es * wv2;
        av[2][0] += v0 * esw; av[2][1] += v1 * esw; av[2][2] += v2 * esw;
    }

    __shared__ float red[4 * 768];
    float* my = red + wid * 768;
    my[lane]        = as0;
    my[64 + lane]   = as1;
    my[128 + lane]  = as2;
#pragma unroll
    for (int c = 0; c < 3; ++c) {
        const int b = 192 + (c * 64 + lane) * 3;
        my[b + 0] = av[c][0];
        my[b + 1] = av[c][1];
        my[b + 2] = av[c][2];
    }
    __syncthreads();

    float* orow = out + (size_t)n * 768;
    for (int j = threadIdx.x; j < 768; j += 256) {
        float v = red[j] + red[768 + j] + red[1536 + j] + red[2304 + j];
        if (p0 == 0) orow[j] = v;
        else         orow[j] += v;
    }
}

// ---------------------------------------------------------------------------
extern "C" void kernel_launch(void* const* d_in, const int* in_sizes, int n_in,
                              void* d_out, int out_size, void* d_ws, size_t ws_size,
                              hipStream_t stream) {
    const float* node_feats    = (const float*)d_in[0];
    const float* edge_features = (const float*)d_in[1];
    const float* radial        = (const float*)d_in[2];
    const float* w1            = (const float*)d_in[3];
    const float* w2            = (const float*)d_in[4];
    const float* w3            = (const float*)d_in[5];
    const int*   senders       = (const int*)d_in[6];
    const int*   receivers     = (const int*)d_in[7];
    float* out = (float*)d_out;

    // ws layout: [counts N][offsets N+1][cursor N][sorted E] | [w2p 8192][w3p 49152] | [wbuf bf16]
    int* counts  = (int*)d_ws;
    int* offsets = counts + N_NODES;
    int* cursor  = offsets + N_NODES + 1;
    int* sorted  = cursor + N_NODES;
    size_t int_bytes = (size_t)((char*)(sorted + N_EDGES) - (char*)d_ws);
    size_t pk_off = (int_bytes + 255) & ~(size_t)255;
    unsigned short* w2p = (unsigned short*)((char*)d_ws + pk_off);
    unsigned short* w3p = w2p + 8192;
    size_t wbuf_off = (pk_off + (8192 + 49152) * sizeof(unsigned short) + 255) & ~(size_t)255;
    unsigned short* wbuf = (unsigned short*)((char*)d_ws + wbuf_off);

    hipMemsetAsync(counts, 0, (size_t)N_NODES * sizeof(int), stream);
    hist_kernel<<<(N_EDGES + 255) / 256, 256, 0, stream>>>(receivers, counts);
    pack_kernel<<<112, 256, 0, stream>>>(w2, w3, w2p, w3p);
    scan_kernel<<<1, 256, 0, stream>>>(counts, offsets, cursor);
    fill_kernel<<<(N_EDGES + 255) / 256, 256, 0, stream>>>(receivers, cursor, sorted);

    size_t avail = (ws_size > wbuf_off) ? (ws_size - wbuf_off) : 0;
    size_t max_chunk = avail / (NUM_IRREPS * sizeof(unsigned short));
    max_chunk &= ~(size_t)(TE - 1);
    int chunk = (max_chunk >= (size_t)N_EDGES) ? N_EDGES
              : (max_chunk < (size_t)TE ? TE : (int)max_chunk);

    for (int p0 = 0; p0 < N_EDGES; p0 += chunk) {
        int cnt = N_EDGES - p0;
        if (cnt > chunk) cnt = chunk;
        int nb1 = (cnt + TE - 1) / TE;
        mlp_kernel<<<nb1, 256, 0, stream>>>(radial, w1, w2p, w3p, sorted, wbuf, p0);
        accum_kernel<<<N_NODES, 256, 0, stream>>>(node_feats, edge_features, wbuf,
                                                  senders, sorted, offsets, out, p0, cnt);
    }
}